// Round 2
// baseline (701.570 us; speedup 1.0000x reference)
//
#include <hip/hip_runtime.h>
#include <cstdint>

#define BLOCK_SIZE 256
#define NPOS 63   // 9*7 spatial positions per batch
#define BPB  16   // batches per block = 4 waves x 4 iterations

typedef __attribute__((ext_vector_type(8))) _Float16 f16x8;     // 8 f16, 4 VGPRs
typedef __attribute__((ext_vector_type(4))) float f32x4;
typedef __attribute__((ext_vector_type(4))) unsigned int uint4v;

// f32 -> f16 RNE bits (low 16) — v_cvt_f16_f32 (default RNE)
__device__ __forceinline__ unsigned rne_f16(float a) {
    _Float16 h = (_Float16)a;
    return (unsigned)__builtin_bit_cast(unsigned short, h);
}
// pack two f32 -> 2 f16 RTZ in ONE v_cvt_pkrtz_f16_f32 (short0=a, short1=b)
__device__ __forceinline__ unsigned pack_f16(float a, float b) {
    auto t = __builtin_amdgcn_cvt_pkrtz(a, b);
    return __builtin_bit_cast(unsigned, t);
}

// R15 -> R16: PERSISTENT MULTI-BATCH WAVES. Counters showed ~2000 VALU
// instr/wave vs ~800 of actual math: the difference is per-wave fixed
// overhead (W2 staging per block, ~26 weight vector-loads per wave,
// gcn_W/ctx_W reloads, block churn at 2.4 waves/SIMD resident).
//  - grid = B/16; each block stages W2 ONCE, each wave loops 4 batches.
//  - W1/b1/b2/W3/b3 + gcn_W column (7) + ctx_W column (45, statically
//    indexed -> VGPRs) + biases hoisted OUTSIDE the batch loop.
//  - b is wave-uniform: ctx row -> s_load_dwordx*, global bases in SGPRs,
//    per-lane voffsets loop-invariant => per-batch address VALU ~ 0.
//  - __launch_bounds__(256, 8): 8 blocks/CU resident (VGPR cap 256).
// Math per batch is bit-identical to R15 (same f16 single-product MFMA).
__global__ __launch_bounds__(BLOCK_SIZE, 8) void carnet_fused(
    const float* __restrict__ x,      // (B, 9, 7) flat
    const int*   __restrict__ adj,    // (B, 45)
    const float* __restrict__ ctx,    // (B, 45)
    const float* __restrict__ gcn_W,  // (7, 7)
    const float* __restrict__ gcn_b,  // (7)
    const float* __restrict__ ctx_W,  // (45, 63)
    const float* __restrict__ ctx_b,  // (63)
    const float* __restrict__ W1,     // (64, 2)
    const float* __restrict__ b1,     // (64)
    const float* __restrict__ W2,     // (64, 64)
    const float* __restrict__ b2,     // (64)
    const float* __restrict__ W3,     // (2, 64)
    const float* __restrict__ b3,     // (2)
    float* __restrict__ out,          // (B, 2, 9, 7) flat
    const int nbatch)
{
    __shared__ short sh2b[64 * 64];   // 8192 B, XOR-swizzled, RNE f16 of W2

    const int t    = threadIdx.x;
    const int lane = t & 63;

    // ---- staging: W2 fp32 -> RNE f16 plane, swizzled LDS write (once) ----
    {
        const int r  = t >> 2;
        const int cq = t & 3;
        const float* wsrc = W2 + r * 64 + cq * 16;
        const float4 w0 = ((const float4*)wsrc)[0];
        const float4 w1 = ((const float4*)wsrc)[1];
        const float4 w2v = ((const float4*)wsrc)[2];
        const float4 w3v = ((const float4*)wsrc)[3];
        uint4v hA = { rne_f16(w0.x)  | (rne_f16(w0.y)  << 16),
                      rne_f16(w0.z)  | (rne_f16(w0.w)  << 16),
                      rne_f16(w1.x)  | (rne_f16(w1.y)  << 16),
                      rne_f16(w1.z)  | (rne_f16(w1.w)  << 16) };
        uint4v hB = { rne_f16(w2v.x) | (rne_f16(w2v.y) << 16),
                      rne_f16(w2v.z) | (rne_f16(w2v.w) << 16),
                      rne_f16(w3v.x) | (rne_f16(w3v.y) << 16),
                      rne_f16(w3v.z) | (rne_f16(w3v.w) << 16) };
        const int sA = ((2 * cq)     ^ (r & 7)) * 8;
        const int sB = ((2 * cq + 1) ^ (r & 7)) * 8;
        *(uint4v*)&sh2b[r * 64 + sA] = hA;
        *(uint4v*)&sh2b[r * 64 + sB] = hB;
    }

    // ---- per-lane loop-invariant constants ----
    const int p = lane < 63 ? lane : 62;
    const int n = p / 7;
    const int f = p - n * 7;
    const int snn = 9 * n - (n * (n - 1)) / 2 - n;

    // hoisted per-lane weight columns (statically indexed -> registers)
    float gw[7];
#pragma unroll
    for (int k = 0; k < 7; ++k) gw[k] = gcn_W[k * 7 + f];
    const float gb = gcn_b[f];
    float ctxw[45];
#pragma unroll
    for (int q = 0; q < 45; ++q) ctxw[q] = ctx_W[q * 63 + p];
    const float cbias = ctx_b[p];

    // ---- phase-2 weight registers (hoisted, R13-proven layout) ----
    const int cl   = lane & 15;       // position within i-tile (B-operand n)
    const int quad = lane >> 4;       // k-octet / C row group (channel)
    const int s0 = (quad ^ (cl & 7)) * 16;

    float2 wp0[8], wp1[8];
    float  bb0[8], bb1[8];
#pragma unroll
    for (int j = 0; j < 8; ++j) {
        const int o = quad * 8 + j;
        wp0[j] = *(const float2*)(W1 + 2 * o);
        bb0[j] = b1[o];
        wp1[j] = *(const float2*)(W1 + 2 * (o + 32));
        bb1[j] = b1[o + 32];
    }

    const float4 b2q0 = *(const float4*)(b2 + quad * 4);
    const float4 b2q1 = *(const float4*)(b2 + 16 + quad * 4);
    const float4 b2q2 = *(const float4*)(b2 + 32 + quad * 4);
    const float4 b2q3 = *(const float4*)(b2 + 48 + quad * 4);
    const float4 wa0 = *(const float4*)(W3 + quad * 4);
    const float4 wa1 = *(const float4*)(W3 + 16 + quad * 4);
    const float4 wa2 = *(const float4*)(W3 + 32 + quad * 4);
    const float4 wa3 = *(const float4*)(W3 + 48 + quad * 4);
    const float4 wb0 = *(const float4*)(W3 + 64 + quad * 4);
    const float4 wb1 = *(const float4*)(W3 + 80 + quad * 4);
    const float4 wb2 = *(const float4*)(W3 + 96 + quad * 4);
    const float4 wb3 = *(const float4*)(W3 + 112 + quad * 4);
    const float b30 = b3[0], b31 = b3[1];

    const char* sh2bB = (const char*)sh2b;

    __syncthreads();   // staging complete before first B read (once)

    const int b0 = blockIdx.x * BPB + (t >> 6);   // this wave's first batch

#pragma unroll 1
    for (int it = 0; it < 4; ++it) {
        const int b = __builtin_amdgcn_readfirstlane(b0 + it * 4);
        if (b >= nbatch) break;

        // ============== PHASE 1: z, c (R10-proven, wave = batch) ==========
        const int* ab = adj + b * 45;
        int aval = 0;
        if (lane < 45) aval = ab[lane];
        const uint64_t am = __ballot(aval != 0);

        float d[9];
#pragma unroll
        for (int i = 0; i < 9; ++i) {
            const int s = 9 * i - (i * (i - 1)) / 2;
            const int w = 8 - i;
            const uint64_t bits = (am >> (s + 1)) & ((1ull << w) - 1ull);
            d[i] = __frsqrt_rn((float)(1 + __popcll(bits)));
        }

        const float* xb = x + b * 63;
        float yv = 0.f;
#pragma unroll
        for (int k = 0; k < 7; ++k)
            yv = fmaf(xb[n * 7 + k], gw[k], yv);

        float zt = 0.f;
#pragma unroll
        for (int m = 0; m < 9; ++m) {
            const float ym = __shfl(yv, m * 7 + f);
            int sh = snn + m;
            sh = sh < 0 ? 0 : sh;
            const bool conn = (m == n) || ((m > n) && ((am >> sh) & 1ull));
            zt = fmaf(conn ? d[m] : 0.f, ym, zt);
        }
        const float zv = fmaf(d[n], zt, gb);

        // ctx dot with 4 accumulators; cb[] is wave-uniform -> s_loads
        const float* cb = ctx + b * 45;
        float ca0 = cbias, ca1 = 0.f, ca2 = 0.f, ca3 = 0.f;
#pragma unroll
        for (int q = 0; q < 44; q += 4) {
            ca0 = fmaf(cb[q],     ctxw[q],     ca0);
            ca1 = fmaf(cb[q + 1], ctxw[q + 1], ca1);
            ca2 = fmaf(cb[q + 2], ctxw[q + 2], ca2);
            ca3 = fmaf(cb[q + 3], ctxw[q + 3], ca3);
        }
        ca0 = fmaf(cb[44], ctxw[44], ca0);
        const float cvv = fmaxf((ca0 + ca1) + (ca2 + ca3), 0.f);

        float* __restrict__ ob = out + b * 126;

        // ============== PHASE 2: MFMA (operand-swapped, f16 single) =======
#pragma unroll 2
        for (int i = 0; i < 4; ++i) {
            const float zm = __shfl(zv,  i * 16 + cl);
            const float cm = __shfl(cvv, i * 16 + cl);

            // h1 fragments (MFMA B operand): single f16 product, cvt_pkrtz
            uint4v ph0, ph1;
#pragma unroll
            for (int jj = 0; jj < 4; ++jj) {
                float ha = fmaxf(fmaf(wp0[2*jj].x,   zm, fmaf(wp0[2*jj].y,   cm, bb0[2*jj])),   0.f);
                float hb = fmaxf(fmaf(wp0[2*jj+1].x, zm, fmaf(wp0[2*jj+1].y, cm, bb0[2*jj+1])), 0.f);
                ph0[jj] = pack_f16(ha, hb);

                ha = fmaxf(fmaf(wp1[2*jj].x,   zm, fmaf(wp1[2*jj].y,   cm, bb1[2*jj])),   0.f);
                hb = fmaxf(fmaf(wp1[2*jj+1].x, zm, fmaf(wp1[2*jj+1].y, cm, bb1[2*jj+1])), 0.f);
                ph1[jj] = pack_f16(ha, hb);
            }
            const f16x8 ah0 = __builtin_bit_cast(f16x8, ph0);
            const f16x8 ah1 = __builtin_bit_cast(f16x8, ph1);

            f32x4 acc0 = {b2q0.x, b2q0.y, b2q0.z, b2q0.w};
            f32x4 acc1 = {b2q1.x, b2q1.y, b2q1.z, b2q1.w};
            f32x4 acc2 = {b2q2.x, b2q2.y, b2q2.z, b2q2.w};
            f32x4 acc3 = {b2q3.x, b2q3.y, b2q3.z, b2q3.w};

            // A = W2 f16 frag (LDS, 2 reads/STEP), B = h1 f16 (2 MFMAs/STEP).
#define STEP(nt) {                                                                    \
            int bo = cl * 128 + s0;                                                   \
            asm volatile("" : "+v"(bo));                                              \
            const int bo2 = (cl * 128) | (s0 ^ 64);                                   \
            const f16x8 wf0 = *(const f16x8*)(sh2bB + bo  + ((nt) * 2048));           \
            const f16x8 wf1 = *(const f16x8*)(sh2bB + bo2 + ((nt) * 2048));           \
            acc##nt = __builtin_amdgcn_mfma_f32_16x16x32_f16(wf0, ah0, acc##nt, 0, 0, 0); \
            acc##nt = __builtin_amdgcn_mfma_f32_16x16x32_f16(wf1, ah1, acc##nt, 0, 0, 0); }
            STEP(0) STEP(1) STEP(2) STEP(3)
#undef STEP

            // Epilogue (channel-major, R13-proven): register-local relu + W3
            // dot, then sum over 4 quads via shfl_xor(16/32); quad 0 stores.
            float q0, q1;
            {
                float h;
                h = fmaxf(acc0[0], 0.f); q0 = h * wa0.x;            q1 = h * wb0.x;
                h = fmaxf(acc0[1], 0.f); q0 = fmaf(h, wa0.y, q0);   q1 = fmaf(h, wb0.y, q1);
                h = fmaxf(acc0[2], 0.f); q0 = fmaf(h, wa0.z, q0);   q1 = fmaf(h, wb0.z, q1);
                h = fmaxf(acc0[3], 0.f); q0 = fmaf(h, wa0.w, q0);   q1 = fmaf(h, wb0.w, q1);
                h = fmaxf(acc1[0], 0.f); q0 = fmaf(h, wa1.x, q0);   q1 = fmaf(h, wb1.x, q1);
                h = fmaxf(acc1[1], 0.f); q0 = fmaf(h, wa1.y, q0);   q1 = fmaf(h, wb1.y, q1);
                h = fmaxf(acc1[2], 0.f); q0 = fmaf(h, wa1.z, q0);   q1 = fmaf(h, wb1.z, q1);
                h = fmaxf(acc1[3], 0.f); q0 = fmaf(h, wa1.w, q0);   q1 = fmaf(h, wb1.w, q1);
                h = fmaxf(acc2[0], 0.f); q0 = fmaf(h, wa2.x, q0);   q1 = fmaf(h, wb2.x, q1);
                h = fmaxf(acc2[1], 0.f); q0 = fmaf(h, wa2.y, q0);   q1 = fmaf(h, wb2.y, q1);
                h = fmaxf(acc2[2], 0.f); q0 = fmaf(h, wa2.z, q0);   q1 = fmaf(h, wb2.z, q1);
                h = fmaxf(acc2[3], 0.f); q0 = fmaf(h, wa2.w, q0);   q1 = fmaf(h, wb2.w, q1);
                h = fmaxf(acc3[0], 0.f); q0 = fmaf(h, wa3.x, q0);   q1 = fmaf(h, wb3.x, q1);
                h = fmaxf(acc3[1], 0.f); q0 = fmaf(h, wa3.y, q0);   q1 = fmaf(h, wb3.y, q1);
                h = fmaxf(acc3[2], 0.f); q0 = fmaf(h, wa3.z, q0);   q1 = fmaf(h, wb3.z, q1);
                h = fmaxf(acc3[3], 0.f); q0 = fmaf(h, wa3.w, q0);   q1 = fmaf(h, wb3.w, q1);
            }
            q0 += __shfl_xor(q0, 16); q0 += __shfl_xor(q0, 32);
            q1 += __shfl_xor(q1, 16); q1 += __shfl_xor(q1, 32);

            const int pp = i * 16 + cl;
            if (quad == 0 && pp < NPOS) {
                ob[pp]        = q0 + b30;
                ob[NPOS + pp] = q1 + b31;
            }
        }
    }
}

extern "C" void kernel_launch(void* const* d_in, const int* in_sizes, int n_in,
                              void* d_out, int out_size, void* d_ws, size_t ws_size,
                              hipStream_t stream) {
    const float* x     = (const float*)d_in[0];
    const int*   adj   = (const int*)  d_in[1];
    const float* ctx   = (const float*)d_in[2];
    const float* gcn_W = (const float*)d_in[3];
    const float* gcn_b = (const float*)d_in[4];
    const float* ctx_W = (const float*)d_in[5];
    const float* ctx_b = (const float*)d_in[6];
    const float* W1    = (const float*)d_in[7];
    const float* b1    = (const float*)d_in[8];
    const float* W2    = (const float*)d_in[9];
    const float* b2    = (const float*)d_in[10];
    const float* W3    = (const float*)d_in[11];
    const float* b3    = (const float*)d_in[12];
    float* out = (float*)d_out;

    const int nbatch = in_sizes[1] / 45;            // B = 32768
    const int grid = (nbatch + BPB - 1) / BPB;      // 16 batches per block
    carnet_fused<<<grid, BLOCK_SIZE, 0, stream>>>(
        x, adj, ctx, gcn_W, gcn_b, ctx_W, ctx_b,
        W1, b1, W2, b2, W3, b3, out, nbatch);
}

// Round 3
// 205.441 us; speedup vs baseline: 3.4149x; 3.4149x over previous
//
#include <hip/hip_runtime.h>
#include <cstdint>

#define BLOCK_SIZE 256
#define NPOS 63   // 9*7 spatial positions per batch
#define BPB  16   // batches per block = 4 waves x 4 iterations

typedef __attribute__((ext_vector_type(8))) _Float16 f16x8;     // 8 f16, 4 VGPRs
typedef __attribute__((ext_vector_type(4))) float f32x4;
typedef __attribute__((ext_vector_type(4))) unsigned int uint4v;

// f32 -> f16 RNE bits (low 16) — v_cvt_f16_f32 (default RNE)
__device__ __forceinline__ unsigned rne_f16(float a) {
    _Float16 h = (_Float16)a;
    return (unsigned)__builtin_bit_cast(unsigned short, h);
}
// pack two f32 -> 2 f16 RTZ in ONE v_cvt_pkrtz_f16_f32 (short0=a, short1=b)
__device__ __forceinline__ unsigned pack_f16(float a, float b) {
    auto t = __builtin_amdgcn_cvt_pkrtz(a, b);
    return __builtin_bit_cast(unsigned, t);
}

// R16 -> R17: FIX THE SPILL. R16's __launch_bounds__(256,8) capped the
// allocator at 512/8=64 VGPRs -> massive scratch spill (VGPR_Count=32,
// FETCH 1.5 GB, 626 us). Persistent structure was RIGHT (occupancy hit
// 90%); the register budget was wrong.
//  - __launch_bounds__(256) only: allocator free, expect ~100 VGPR
//    (5 waves/SIMD cap), ZERO spill.
//  - ctxw[45] hoist DROPPED (45 VGPRs): ctx_W is 11 KB, L1-resident;
//    per-batch per-lane reloads cost VMEM issue only.
//  - kept hoists: gw[7], gcn_b, ctx_b (9 VGPR) + phase-2 weights (R15's
//    natural 80-VGPR footprint).
//  - grid = B/16 persistent blocks; W2 staged once; wave loops 4 batches.
// Math per batch is bit-identical to R15 (same f16 single-product MFMA).
__global__ __launch_bounds__(BLOCK_SIZE) void carnet_fused(
    const float* __restrict__ x,      // (B, 9, 7) flat
    const int*   __restrict__ adj,    // (B, 45)
    const float* __restrict__ ctx,    // (B, 45)
    const float* __restrict__ gcn_W,  // (7, 7)
    const float* __restrict__ gcn_b,  // (7)
    const float* __restrict__ ctx_W,  // (45, 63)
    const float* __restrict__ ctx_b,  // (63)
    const float* __restrict__ W1,     // (64, 2)
    const float* __restrict__ b1,     // (64)
    const float* __restrict__ W2,     // (64, 64)
    const float* __restrict__ b2,     // (64)
    const float* __restrict__ W3,     // (2, 64)
    const float* __restrict__ b3,     // (2)
    float* __restrict__ out,          // (B, 2, 9, 7) flat
    const int nbatch)
{
    __shared__ short sh2b[64 * 64];   // 8192 B, XOR-swizzled, RNE f16 of W2

    const int t    = threadIdx.x;
    const int lane = t & 63;

    // ---- staging: W2 fp32 -> RNE f16 plane, swizzled LDS write (once) ----
    {
        const int r  = t >> 2;
        const int cq = t & 3;
        const float* wsrc = W2 + r * 64 + cq * 16;
        const float4 w0 = ((const float4*)wsrc)[0];
        const float4 w1 = ((const float4*)wsrc)[1];
        const float4 w2v = ((const float4*)wsrc)[2];
        const float4 w3v = ((const float4*)wsrc)[3];
        uint4v hA = { rne_f16(w0.x)  | (rne_f16(w0.y)  << 16),
                      rne_f16(w0.z)  | (rne_f16(w0.w)  << 16),
                      rne_f16(w1.x)  | (rne_f16(w1.y)  << 16),
                      rne_f16(w1.z)  | (rne_f16(w1.w)  << 16) };
        uint4v hB = { rne_f16(w2v.x) | (rne_f16(w2v.y) << 16),
                      rne_f16(w2v.z) | (rne_f16(w2v.w) << 16),
                      rne_f16(w3v.x) | (rne_f16(w3v.y) << 16),
                      rne_f16(w3v.z) | (rne_f16(w3v.w) << 16) };
        const int sA = ((2 * cq)     ^ (r & 7)) * 8;
        const int sB = ((2 * cq + 1) ^ (r & 7)) * 8;
        *(uint4v*)&sh2b[r * 64 + sA] = hA;
        *(uint4v*)&sh2b[r * 64 + sB] = hB;
    }

    // ---- per-lane loop-invariant constants ----
    const int p = lane < 63 ? lane : 62;
    const int n = p / 7;
    const int f = p - n * 7;
    const int snn = 9 * n - (n * (n - 1)) / 2 - n;

    // hoisted per-lane weight columns (small, statically indexed)
    float gw[7];
#pragma unroll
    for (int k = 0; k < 7; ++k) gw[k] = gcn_W[k * 7 + f];
    const float gb = gcn_b[f];
    const float cbias = ctx_b[p];

    // ---- phase-2 weight registers (hoisted, R13-proven layout) ----
    const int cl   = lane & 15;       // position within i-tile (B-operand n)
    const int quad = lane >> 4;       // k-octet / C row group (channel)
    const int s0 = (quad ^ (cl & 7)) * 16;

    float2 wp0[8], wp1[8];
    float  bb0[8], bb1[8];
#pragma unroll
    for (int j = 0; j < 8; ++j) {
        const int o = quad * 8 + j;
        wp0[j] = *(const float2*)(W1 + 2 * o);
        bb0[j] = b1[o];
        wp1[j] = *(const float2*)(W1 + 2 * (o + 32));
        bb1[j] = b1[o + 32];
    }

    const float4 b2q0 = *(const float4*)(b2 + quad * 4);
    const float4 b2q1 = *(const float4*)(b2 + 16 + quad * 4);
    const float4 b2q2 = *(const float4*)(b2 + 32 + quad * 4);
    const float4 b2q3 = *(const float4*)(b2 + 48 + quad * 4);
    const float4 wa0 = *(const float4*)(W3 + quad * 4);
    const float4 wa1 = *(const float4*)(W3 + 16 + quad * 4);
    const float4 wa2 = *(const float4*)(W3 + 32 + quad * 4);
    const float4 wa3 = *(const float4*)(W3 + 48 + quad * 4);
    const float4 wb0 = *(const float4*)(W3 + 64 + quad * 4);
    const float4 wb1 = *(const float4*)(W3 + 80 + quad * 4);
    const float4 wb2 = *(const float4*)(W3 + 96 + quad * 4);
    const float4 wb3 = *(const float4*)(W3 + 112 + quad * 4);
    const float b30 = b3[0], b31 = b3[1];

    const char* sh2bB = (const char*)sh2b;

    __syncthreads();   // staging complete before first B read (once)

    const int b0 = blockIdx.x * BPB + (t >> 6);   // this wave's first batch

#pragma unroll 1
    for (int it = 0; it < 4; ++it) {
        const int b = __builtin_amdgcn_readfirstlane(b0 + it * 4);
        if (b >= nbatch) break;

        // ============== PHASE 1: z, c (R10-proven, wave = batch) ==========
        const int* ab = adj + b * 45;
        int aval = 0;
        if (lane < 45) aval = ab[lane];
        const uint64_t am = __ballot(aval != 0);

        float d[9];
#pragma unroll
        for (int i = 0; i < 9; ++i) {
            const int s = 9 * i - (i * (i - 1)) / 2;
            const int w = 8 - i;
            const uint64_t bits = (am >> (s + 1)) & ((1ull << w) - 1ull);
            d[i] = __frsqrt_rn((float)(1 + __popcll(bits)));
        }

        const float* xb = x + b * 63;
        float yv = 0.f;
#pragma unroll
        for (int k = 0; k < 7; ++k)
            yv = fmaf(xb[n * 7 + k], gw[k], yv);

        float zt = 0.f;
#pragma unroll
        for (int m = 0; m < 9; ++m) {
            const float ym = __shfl(yv, m * 7 + f);
            int sh = snn + m;
            sh = sh < 0 ? 0 : sh;
            const bool conn = (m == n) || ((m > n) && ((am >> sh) & 1ull));
            zt = fmaf(conn ? d[m] : 0.f, ym, zt);
        }
        const float zv = fmaf(d[n], zt, gb);

        // ctx dot with 4 accumulators; cb[] wave-uniform -> scalar loads,
        // ctx_W per-lane columns are L1-resident (11 KB weight)
        const float* cb = ctx + b * 45;
        float ca0 = cbias, ca1 = 0.f, ca2 = 0.f, ca3 = 0.f;
#pragma unroll
        for (int q = 0; q < 44; q += 4) {
            ca0 = fmaf(cb[q],     ctx_W[q * 63 + p],       ca0);
            ca1 = fmaf(cb[q + 1], ctx_W[(q + 1) * 63 + p], ca1);
            ca2 = fmaf(cb[q + 2], ctx_W[(q + 2) * 63 + p], ca2);
            ca3 = fmaf(cb[q + 3], ctx_W[(q + 3) * 63 + p], ca3);
        }
        ca0 = fmaf(cb[44], ctx_W[44 * 63 + p], ca0);
        const float cvv = fmaxf((ca0 + ca1) + (ca2 + ca3), 0.f);

        float* __restrict__ ob = out + b * 126;

        // ============== PHASE 2: MFMA (operand-swapped, f16 single) =======
#pragma unroll 2
        for (int i = 0; i < 4; ++i) {
            const float zm = __shfl(zv,  i * 16 + cl);
            const float cm = __shfl(cvv, i * 16 + cl);

            // h1 fragments (MFMA B operand): single f16 product, cvt_pkrtz
            uint4v ph0, ph1;
#pragma unroll
            for (int jj = 0; jj < 4; ++jj) {
                float ha = fmaxf(fmaf(wp0[2*jj].x,   zm, fmaf(wp0[2*jj].y,   cm, bb0[2*jj])),   0.f);
                float hb = fmaxf(fmaf(wp0[2*jj+1].x, zm, fmaf(wp0[2*jj+1].y, cm, bb0[2*jj+1])), 0.f);
                ph0[jj] = pack_f16(ha, hb);

                ha = fmaxf(fmaf(wp1[2*jj].x,   zm, fmaf(wp1[2*jj].y,   cm, bb1[2*jj])),   0.f);
                hb = fmaxf(fmaf(wp1[2*jj+1].x, zm, fmaf(wp1[2*jj+1].y, cm, bb1[2*jj+1])), 0.f);
                ph1[jj] = pack_f16(ha, hb);
            }
            const f16x8 ah0 = __builtin_bit_cast(f16x8, ph0);
            const f16x8 ah1 = __builtin_bit_cast(f16x8, ph1);

            f32x4 acc0 = {b2q0.x, b2q0.y, b2q0.z, b2q0.w};
            f32x4 acc1 = {b2q1.x, b2q1.y, b2q1.z, b2q1.w};
            f32x4 acc2 = {b2q2.x, b2q2.y, b2q2.z, b2q2.w};
            f32x4 acc3 = {b2q3.x, b2q3.y, b2q3.z, b2q3.w};

            // A = W2 f16 frag (LDS, 2 reads/STEP), B = h1 f16 (2 MFMAs/STEP).
#define STEP(nt) {                                                                    \
            int bo = cl * 128 + s0;                                                   \
            asm volatile("" : "+v"(bo));                                              \
            const int bo2 = (cl * 128) | (s0 ^ 64);                                   \
            const f16x8 wf0 = *(const f16x8*)(sh2bB + bo  + ((nt) * 2048));           \
            const f16x8 wf1 = *(const f16x8*)(sh2bB + bo2 + ((nt) * 2048));           \
            acc##nt = __builtin_amdgcn_mfma_f32_16x16x32_f16(wf0, ah0, acc##nt, 0, 0, 0); \
            acc##nt = __builtin_amdgcn_mfma_f32_16x16x32_f16(wf1, ah1, acc##nt, 0, 0, 0); }
            STEP(0) STEP(1) STEP(2) STEP(3)
#undef STEP

            // Epilogue (channel-major, R13-proven): register-local relu + W3
            // dot, then sum over 4 quads via shfl_xor(16/32); quad 0 stores.
            float q0, q1;
            {
                float h;
                h = fmaxf(acc0[0], 0.f); q0 = h * wa0.x;            q1 = h * wb0.x;
                h = fmaxf(acc0[1], 0.f); q0 = fmaf(h, wa0.y, q0);   q1 = fmaf(h, wb0.y, q1);
                h = fmaxf(acc0[2], 0.f); q0 = fmaf(h, wa0.z, q0);   q1 = fmaf(h, wb0.z, q1);
                h = fmaxf(acc0[3], 0.f); q0 = fmaf(h, wa0.w, q0);   q1 = fmaf(h, wb0.w, q1);
                h = fmaxf(acc1[0], 0.f); q0 = fmaf(h, wa1.x, q0);   q1 = fmaf(h, wb1.x, q1);
                h = fmaxf(acc1[1], 0.f); q0 = fmaf(h, wa1.y, q0);   q1 = fmaf(h, wb1.y, q1);
                h = fmaxf(acc1[2], 0.f); q0 = fmaf(h, wa1.z, q0);   q1 = fmaf(h, wb1.z, q1);
                h = fmaxf(acc1[3], 0.f); q0 = fmaf(h, wa1.w, q0);   q1 = fmaf(h, wb1.w, q1);
                h = fmaxf(acc2[0], 0.f); q0 = fmaf(h, wa2.x, q0);   q1 = fmaf(h, wb2.x, q1);
                h = fmaxf(acc2[1], 0.f); q0 = fmaf(h, wa2.y, q0);   q1 = fmaf(h, wb2.y, q1);
                h = fmaxf(acc2[2], 0.f); q0 = fmaf(h, wa2.z, q0);   q1 = fmaf(h, wb2.z, q1);
                h = fmaxf(acc2[3], 0.f); q0 = fmaf(h, wa2.w, q0);   q1 = fmaf(h, wb2.w, q1);
                h = fmaxf(acc3[0], 0.f); q0 = fmaf(h, wa3.x, q0);   q1 = fmaf(h, wb3.x, q1);
                h = fmaxf(acc3[1], 0.f); q0 = fmaf(h, wa3.y, q0);   q1 = fmaf(h, wb3.y, q1);
                h = fmaxf(acc3[2], 0.f); q0 = fmaf(h, wa3.z, q0);   q1 = fmaf(h, wb3.z, q1);
                h = fmaxf(acc3[3], 0.f); q0 = fmaf(h, wa3.w, q0);   q1 = fmaf(h, wb3.w, q1);
            }
            q0 += __shfl_xor(q0, 16); q0 += __shfl_xor(q0, 32);
            q1 += __shfl_xor(q1, 16); q1 += __shfl_xor(q1, 32);

            const int pp = i * 16 + cl;
            if (quad == 0 && pp < NPOS) {
                ob[pp]        = q0 + b30;
                ob[NPOS + pp] = q1 + b31;
            }
        }
    }
}

extern "C" void kernel_launch(void* const* d_in, const int* in_sizes, int n_in,
                              void* d_out, int out_size, void* d_ws, size_t ws_size,
                              hipStream_t stream) {
    const float* x     = (const float*)d_in[0];
    const int*   adj   = (const int*)  d_in[1];
    const float* ctx   = (const float*)d_in[2];
    const float* gcn_W = (const float*)d_in[3];
    const float* gcn_b = (const float*)d_in[4];
    const float* ctx_W = (const float*)d_in[5];
    const float* ctx_b = (const float*)d_in[6];
    const float* W1    = (const float*)d_in[7];
    const float* b1    = (const float*)d_in[8];
    const float* W2    = (const float*)d_in[9];
    const float* b2    = (const float*)d_in[10];
    const float* W3    = (const float*)d_in[11];
    const float* b3    = (const float*)d_in[12];
    float* out = (float*)d_out;

    const int nbatch = in_sizes[1] / 45;            // B = 32768
    const int grid = (nbatch + BPB - 1) / BPB;      // 16 batches per block
    carnet_fused<<<grid, BLOCK_SIZE, 0, stream>>>(
        x, adj, ctx, gcn_W, gcn_b, ctx_W, ctx_b,
        W1, b1, W2, b2, W3, b3, out, nbatch);
}

// Round 4
// 183.654 us; speedup vs baseline: 3.8201x; 1.1186x over previous
//
#include <hip/hip_runtime.h>
#include <cstdint>

#define BLOCK_SIZE 512   // 8 waves/block: fewer, fatter blocks -> more resident waves
#define NPOS 63          // 9*7 spatial positions per batch
#define WPB  8           // waves (= batches) per block

typedef __attribute__((ext_vector_type(8))) _Float16 f16x8;     // 8 f16, 4 VGPRs
typedef __attribute__((ext_vector_type(4))) float f32x4;
typedef __attribute__((ext_vector_type(4))) unsigned int uint4v;

// f32 -> f16 RNE bits (low 16) — v_cvt_f16_f32 (default RNE)
__device__ __forceinline__ unsigned rne_f16(float a) {
    _Float16 h = (_Float16)a;
    return (unsigned)__builtin_bit_cast(unsigned short, h);
}
// pack two f32 -> 2 f16 RTZ in ONE v_cvt_pkrtz_f16_f32 (short0=a, short1=b)
__device__ __forceinline__ unsigned pack_f16(float a, float b) {
    auto t = __builtin_amdgcn_cvt_pkrtz(a, b);
    return __builtin_bit_cast(unsigned, t);
}

// R17 -> R18: BLOCK-GRANULARITY OCCUPANCY FIX. R15-R17 evidence:
//  - R15 (32768 blocks, 1 batch/wave): 88 us, occ 30% (~2.4 blocks/CU),
//    VALUBusy 58%. Block turnover = 372 blocks/us ~= CP dispatch rate =>
//    residency is BLOCK-SUPPLY-limited, not VGPR-limited (80 VGPR allows 6
//    waves/SIMD).
//  - R17 (persistent, 4 batches/wave serial): 130 us — TLP loss beats
//    overhead win; serial batch loop exposes cold-miss latency.
// Fix: 512-thread blocks = 8 waves/block, STILL 1 batch/wave (R15's proven
// per-wave code + schedule), grid 4096 => turnover ~60/us, VGPR ~80 =>
// 2-3 blocks/CU can stack 16-24 waves/CU.
// Plus: z-chain split into 3 accumulators (9-deep serial fma -> 3x3, ILP).
__global__ __launch_bounds__(BLOCK_SIZE) void carnet_fused(
    const float* __restrict__ x,      // (B, 9, 7) flat
    const int*   __restrict__ adj,    // (B, 45)
    const float* __restrict__ ctx,    // (B, 45)
    const float* __restrict__ gcn_W,  // (7, 7)
    const float* __restrict__ gcn_b,  // (7)
    const float* __restrict__ ctx_W,  // (45, 63)
    const float* __restrict__ ctx_b,  // (63)
    const float* __restrict__ W1,     // (64, 2)
    const float* __restrict__ b1,     // (64)
    const float* __restrict__ W2,     // (64, 64)
    const float* __restrict__ b2,     // (64)
    const float* __restrict__ W3,     // (2, 64)
    const float* __restrict__ b3,     // (2)
    float* __restrict__ out,          // (B, 2, 9, 7) flat
    const int nbatch)
{
    __shared__ short sh2b[64 * 64];   // 8192 B, XOR-swizzled, RNE f16 of W2

    const int t    = threadIdx.x;
    const int lane = t & 63;

    // ---- staging: W2 fp32 -> RNE f16 plane, swizzled LDS write ----
    // (first 256 threads cover all 64x64; waves 4-7 skip)
    if (t < 256) {
        const int r  = t >> 2;
        const int cq = t & 3;
        const float* wsrc = W2 + r * 64 + cq * 16;
        const float4 w0 = ((const float4*)wsrc)[0];
        const float4 w1 = ((const float4*)wsrc)[1];
        const float4 w2v = ((const float4*)wsrc)[2];
        const float4 w3v = ((const float4*)wsrc)[3];
        uint4v hA = { rne_f16(w0.x)  | (rne_f16(w0.y)  << 16),
                      rne_f16(w0.z)  | (rne_f16(w0.w)  << 16),
                      rne_f16(w1.x)  | (rne_f16(w1.y)  << 16),
                      rne_f16(w1.z)  | (rne_f16(w1.w)  << 16) };
        uint4v hB = { rne_f16(w2v.x) | (rne_f16(w2v.y) << 16),
                      rne_f16(w2v.z) | (rne_f16(w2v.w) << 16),
                      rne_f16(w3v.x) | (rne_f16(w3v.y) << 16),
                      rne_f16(w3v.z) | (rne_f16(w3v.w) << 16) };
        const int sA = ((2 * cq)     ^ (r & 7)) * 8;
        const int sB = ((2 * cq + 1) ^ (r & 7)) * 8;
        *(uint4v*)&sh2b[r * 64 + sA] = hA;
        *(uint4v*)&sh2b[r * 64 + sB] = hB;
    }

    __syncthreads();   // staging complete before any B read (before any return!)

    // ================= PHASE 1: z, c (R10-proven, wave = batch) ==========
    const int b = __builtin_amdgcn_readfirstlane(blockIdx.x * WPB + (t >> 6));
    if (b >= nbatch) return;

    const int p = lane < 63 ? lane : 62;
    const int n = p / 7;
    const int f = p - n * 7;

    // adjacency bitmask: one coalesced lane-load + ballot (bit i = adj[i]!=0)
    const int* ab = adj + b * 45;
    int aval = 0;
    if (lane < 45) aval = ab[lane];
    const uint64_t am = __ballot(aval != 0);

    float d[9];
#pragma unroll
    for (int i = 0; i < 9; ++i) {
        const int s = 9 * i - (i * (i - 1)) / 2;
        const int w = 8 - i;
        const uint64_t bits = (am >> (s + 1)) & ((1ull << w) - 1ull);
        d[i] = __frsqrt_rn((float)(1 + __popcll(bits)));
    }

    const float* xb = x + b * 63;
    float yv = 0.f;
#pragma unroll
    for (int k = 0; k < 7; ++k)
        yv = fmaf(xb[n * 7 + k], gcn_W[k * 7 + f], yv);

    // z dot: 3 independent accumulators (was one 9-deep serial fma chain)
    float zt0 = 0.f, zt1 = 0.f, zt2 = 0.f;
    const int snn = 9 * n - (n * (n - 1)) / 2 - n;
#pragma unroll
    for (int m = 0; m < 9; ++m) {
        const float ym = __shfl(yv, m * 7 + f);
        int sh = snn + m;
        sh = sh < 0 ? 0 : sh;
        const bool conn = (m == n) || ((m > n) && ((am >> sh) & 1ull));
        const float term = conn ? d[m] : 0.f;
        if (m < 3)      zt0 = fmaf(term, ym, zt0);
        else if (m < 6) zt1 = fmaf(term, ym, zt1);
        else            zt2 = fmaf(term, ym, zt2);
    }
    const float zv = fmaf(d[n], (zt0 + zt1) + zt2, gcn_b[f]);

    // ctx dot with 4 accumulators (shorter dependency chain)
    const float* cb = ctx + b * 45;
    float ca0 = ctx_b[p], ca1 = 0.f, ca2 = 0.f, ca3 = 0.f;
#pragma unroll
    for (int q = 0; q < 44; q += 4) {
        ca0 = fmaf(cb[q],     ctx_W[q * 63 + p],       ca0);
        ca1 = fmaf(cb[q + 1], ctx_W[(q + 1) * 63 + p], ca1);
        ca2 = fmaf(cb[q + 2], ctx_W[(q + 2) * 63 + p], ca2);
        ca3 = fmaf(cb[q + 3], ctx_W[(q + 3) * 63 + p], ca3);
    }
    ca0 = fmaf(cb[44], ctx_W[44 * 63 + p], ca0);
    const float cvv = fmaxf((ca0 + ca1) + (ca2 + ca3), 0.f);

    // ================= PHASE 2: MFMA (operand-swapped, f16 single) =======
    const int cl   = lane & 15;       // position within i-tile (B-operand n)
    const int quad = lane >> 4;       // k-octet / C row group (channel)
    const int s0 = (quad ^ (cl & 7)) * 16;

    float2 wp0[8], wp1[8];
    float  bb0[8], bb1[8];
#pragma unroll
    for (int j = 0; j < 8; ++j) {
        const int o = quad * 8 + j;
        wp0[j] = *(const float2*)(W1 + 2 * o);
        bb0[j] = b1[o];
        wp1[j] = *(const float2*)(W1 + 2 * (o + 32));
        bb1[j] = b1[o + 32];
    }

    const float4 b2q0 = *(const float4*)(b2 + quad * 4);
    const float4 b2q1 = *(const float4*)(b2 + 16 + quad * 4);
    const float4 b2q2 = *(const float4*)(b2 + 32 + quad * 4);
    const float4 b2q3 = *(const float4*)(b2 + 48 + quad * 4);
    const float4 wa0 = *(const float4*)(W3 + quad * 4);
    const float4 wa1 = *(const float4*)(W3 + 16 + quad * 4);
    const float4 wa2 = *(const float4*)(W3 + 32 + quad * 4);
    const float4 wa3 = *(const float4*)(W3 + 48 + quad * 4);
    const float4 wb0 = *(const float4*)(W3 + 64 + quad * 4);
    const float4 wb1 = *(const float4*)(W3 + 80 + quad * 4);
    const float4 wb2 = *(const float4*)(W3 + 96 + quad * 4);
    const float4 wb3 = *(const float4*)(W3 + 112 + quad * 4);
    const float b30 = b3[0], b31 = b3[1];
    float* __restrict__ ob = out + b * 126;

    const char* sh2bB = (const char*)sh2b;

#pragma unroll 2
    for (int i = 0; i < 4; ++i) {
        const float zm = __shfl(zv,  i * 16 + cl);
        const float cm = __shfl(cvv, i * 16 + cl);

        // h1 fragments (MFMA B operand): single f16 product, cvt_pkrtz packs
        uint4v ph0, ph1;
#pragma unroll
        for (int jj = 0; jj < 4; ++jj) {
            float ha = fmaxf(fmaf(wp0[2*jj].x,   zm, fmaf(wp0[2*jj].y,   cm, bb0[2*jj])),   0.f);
            float hb = fmaxf(fmaf(wp0[2*jj+1].x, zm, fmaf(wp0[2*jj+1].y, cm, bb0[2*jj+1])), 0.f);
            ph0[jj] = pack_f16(ha, hb);

            ha = fmaxf(fmaf(wp1[2*jj].x,   zm, fmaf(wp1[2*jj].y,   cm, bb1[2*jj])),   0.f);
            hb = fmaxf(fmaf(wp1[2*jj+1].x, zm, fmaf(wp1[2*jj+1].y, cm, bb1[2*jj+1])), 0.f);
            ph1[jj] = pack_f16(ha, hb);
        }
        const f16x8 ah0 = __builtin_bit_cast(f16x8, ph0);
        const f16x8 ah1 = __builtin_bit_cast(f16x8, ph1);

        f32x4 acc0 = {b2q0.x, b2q0.y, b2q0.z, b2q0.w};
        f32x4 acc1 = {b2q1.x, b2q1.y, b2q1.z, b2q1.w};
        f32x4 acc2 = {b2q2.x, b2q2.y, b2q2.z, b2q2.w};
        f32x4 acc3 = {b2q3.x, b2q3.y, b2q3.z, b2q3.w};

        // A = W2 f16 frag (LDS, 2 reads/STEP), B = h1 f16 (2 MFMAs/STEP).
#define STEP(nt) {                                                                    \
        int bo = cl * 128 + s0;                                                       \
        asm volatile("" : "+v"(bo));                                                  \
        const int bo2 = (cl * 128) | (s0 ^ 64);                                       \
        const f16x8 wf0 = *(const f16x8*)(sh2bB + bo  + ((nt) * 2048));               \
        const f16x8 wf1 = *(const f16x8*)(sh2bB + bo2 + ((nt) * 2048));               \
        acc##nt = __builtin_amdgcn_mfma_f32_16x16x32_f16(wf0, ah0, acc##nt, 0, 0, 0); \
        acc##nt = __builtin_amdgcn_mfma_f32_16x16x32_f16(wf1, ah1, acc##nt, 0, 0, 0); }
        STEP(0) STEP(1) STEP(2) STEP(3)
#undef STEP

        // Epilogue (channel-major, R13-proven): register-local relu + W3 dot,
        // then sum over 4 quads via shfl_xor(16/32); quad 0 stores.
        float q0, q1;
        {
            float h;
            h = fmaxf(acc0[0], 0.f); q0 = h * wa0.x;            q1 = h * wb0.x;
            h = fmaxf(acc0[1], 0.f); q0 = fmaf(h, wa0.y, q0);   q1 = fmaf(h, wb0.y, q1);
            h = fmaxf(acc0[2], 0.f); q0 = fmaf(h, wa0.z, q0);   q1 = fmaf(h, wb0.z, q1);
            h = fmaxf(acc0[3], 0.f); q0 = fmaf(h, wa0.w, q0);   q1 = fmaf(h, wb0.w, q1);
            h = fmaxf(acc1[0], 0.f); q0 = fmaf(h, wa1.x, q0);   q1 = fmaf(h, wb1.x, q1);
            h = fmaxf(acc1[1], 0.f); q0 = fmaf(h, wa1.y, q0);   q1 = fmaf(h, wb1.y, q1);
            h = fmaxf(acc1[2], 0.f); q0 = fmaf(h, wa1.z, q0);   q1 = fmaf(h, wb1.z, q1);
            h = fmaxf(acc1[3], 0.f); q0 = fmaf(h, wa1.w, q0);   q1 = fmaf(h, wb1.w, q1);
            h = fmaxf(acc2[0], 0.f); q0 = fmaf(h, wa2.x, q0);   q1 = fmaf(h, wb2.x, q1);
            h = fmaxf(acc2[1], 0.f); q0 = fmaf(h, wa2.y, q0);   q1 = fmaf(h, wb2.y, q1);
            h = fmaxf(acc2[2], 0.f); q0 = fmaf(h, wa2.z, q0);   q1 = fmaf(h, wb2.z, q1);
            h = fmaxf(acc2[3], 0.f); q0 = fmaf(h, wa2.w, q0);   q1 = fmaf(h, wb2.w, q1);
            h = fmaxf(acc3[0], 0.f); q0 = fmaf(h, wa3.x, q0);   q1 = fmaf(h, wb3.x, q1);
            h = fmaxf(acc3[1], 0.f); q0 = fmaf(h, wa3.y, q0);   q1 = fmaf(h, wb3.y, q1);
            h = fmaxf(acc3[2], 0.f); q0 = fmaf(h, wa3.z, q0);   q1 = fmaf(h, wb3.z, q1);
            h = fmaxf(acc3[3], 0.f); q0 = fmaf(h, wa3.w, q0);   q1 = fmaf(h, wb3.w, q1);
        }
        q0 += __shfl_xor(q0, 16); q0 += __shfl_xor(q0, 32);
        q1 += __shfl_xor(q1, 16); q1 += __shfl_xor(q1, 32);

        const int pp = i * 16 + cl;
        if (quad == 0 && pp < NPOS) {
            ob[pp]        = q0 + b30;
            ob[NPOS + pp] = q1 + b31;
        }
    }
}

extern "C" void kernel_launch(void* const* d_in, const int* in_sizes, int n_in,
                              void* d_out, int out_size, void* d_ws, size_t ws_size,
                              hipStream_t stream) {
    const float* x     = (const float*)d_in[0];
    const int*   adj   = (const int*)  d_in[1];
    const float* ctx   = (const float*)d_in[2];
    const float* gcn_W = (const float*)d_in[3];
    const float* gcn_b = (const float*)d_in[4];
    const float* ctx_W = (const float*)d_in[5];
    const float* ctx_b = (const float*)d_in[6];
    const float* W1    = (const float*)d_in[7];
    const float* b1    = (const float*)d_in[8];
    const float* W2    = (const float*)d_in[9];
    const float* b2    = (const float*)d_in[10];
    const float* W3    = (const float*)d_in[11];
    const float* b3    = (const float*)d_in[12];
    float* out = (float*)d_out;

    const int nbatch = in_sizes[1] / 45;            // B = 32768
    const int grid = (nbatch + WPB - 1) / WPB;      // 8 batches (waves) per block
    carnet_fused<<<grid, BLOCK_SIZE, 0, stream>>>(
        x, adj, ctx, gcn_W, gcn_b, ctx_W, ctx_b,
        W1, b1, W2, b2, W3, b3, out, nbatch);
}

// Round 5
// 146.387 us; speedup vs baseline: 4.7926x; 1.2546x over previous
//
#include <hip/hip_runtime.h>
#include <cstdint>

#define BLOCK_SIZE 256
#define NPOS 63          // 9*7 spatial positions per batch
#define BPB  8           // batches per block = 4 waves x 2 batches/wave

typedef __attribute__((ext_vector_type(8))) _Float16 f16x8;     // 8 f16, 4 VGPRs
typedef __attribute__((ext_vector_type(4))) float f32x4;
typedef __attribute__((ext_vector_type(4))) unsigned int uint4v;

// f32 -> f16 RNE bits (low 16) — v_cvt_f16_f32 (default RNE)
__device__ __forceinline__ unsigned rne_f16(float a) {
    _Float16 h = (_Float16)a;
    return (unsigned)__builtin_bit_cast(unsigned short, h);
}
// pack two f32 -> 2 f16 RTZ in ONE v_cvt_pkrtz_f16_f32 (short0=a, short1=b)
__device__ __forceinline__ unsigned pack_f16(float a, float b) {
    auto t = __builtin_amdgcn_cvt_pkrtz(a, b);
    return __builtin_bit_cast(unsigned, t);
}

// R18 -> R19: DUAL-BATCH ILP WAVES. Evidence across R15/R17/R18: per-wave
// lifetime is invariant ~6.6 us (~16k cyc) at ~8-10 resident waves/CU in
// EVERY configuration; ~85% of lifetime is stall. Residency can't be
// raised (3 attempts), so widen the wave: each wave processes TWO batches
// with INTERLEAVED (not serial — that was R17's mistake) dependency
// chains. Chain B's work fills chain A's stalls.
// Amortized per pair: weight loads (~26 VMEM), ctx_W col (45), gcn_W (7),
// W2 LDS fragment reads (8 ds_read_b128/i now feed 16 MFMAs), staging.
// Wave count halves (16384); per-wave lifetime should grow only ~1.3x.
// Per-batch arithmetic is bit-identical to R18 (f16 single-product MFMA).
__global__ __launch_bounds__(BLOCK_SIZE) void carnet_fused(
    const float* __restrict__ x,      // (B, 9, 7) flat
    const int*   __restrict__ adj,    // (B, 45)
    const float* __restrict__ ctx,    // (B, 45)
    const float* __restrict__ gcn_W,  // (7, 7)
    const float* __restrict__ gcn_b,  // (7)
    const float* __restrict__ ctx_W,  // (45, 63)
    const float* __restrict__ ctx_b,  // (63)
    const float* __restrict__ W1,     // (64, 2)
    const float* __restrict__ b1,     // (64)
    const float* __restrict__ W2,     // (64, 64)
    const float* __restrict__ b2,     // (64)
    const float* __restrict__ W3,     // (2, 64)
    const float* __restrict__ b3,     // (2)
    float* __restrict__ out,          // (B, 2, 9, 7) flat
    const int nbatch)
{
    __shared__ short sh2b[64 * 64];   // 8192 B, XOR-swizzled, RNE f16 of W2

    const int t    = threadIdx.x;
    const int lane = t & 63;

    // ---- staging: W2 fp32 -> RNE f16 plane, swizzled LDS write ----
    {
        const int r  = t >> 2;
        const int cq = t & 3;
        const float* wsrc = W2 + r * 64 + cq * 16;
        const float4 w0 = ((const float4*)wsrc)[0];
        const float4 w1 = ((const float4*)wsrc)[1];
        const float4 w2v = ((const float4*)wsrc)[2];
        const float4 w3v = ((const float4*)wsrc)[3];
        uint4v hA = { rne_f16(w0.x)  | (rne_f16(w0.y)  << 16),
                      rne_f16(w0.z)  | (rne_f16(w0.w)  << 16),
                      rne_f16(w1.x)  | (rne_f16(w1.y)  << 16),
                      rne_f16(w1.z)  | (rne_f16(w1.w)  << 16) };
        uint4v hB = { rne_f16(w2v.x) | (rne_f16(w2v.y) << 16),
                      rne_f16(w2v.z) | (rne_f16(w2v.w) << 16),
                      rne_f16(w3v.x) | (rne_f16(w3v.y) << 16),
                      rne_f16(w3v.z) | (rne_f16(w3v.w) << 16) };
        const int sA = ((2 * cq)     ^ (r & 7)) * 8;
        const int sB = ((2 * cq + 1) ^ (r & 7)) * 8;
        *(uint4v*)&sh2b[r * 64 + sA] = hA;
        *(uint4v*)&sh2b[r * 64 + sB] = hB;
    }

    // ---- two wave-uniform batches per wave ----
    const int bA = __builtin_amdgcn_readfirstlane(blockIdx.x * BPB + (t >> 6));
    const int bBr = bA + 4;                                    // batch B raw
    const bool hasB = (bBr < nbatch);
    const int bB = __builtin_amdgcn_readfirstlane(hasB ? bBr : bA);

    const int p = lane < 63 ? lane : 62;
    const int n = p / 7;
    const int f = p - n * 7;

    // ========== PHASE 1 (dual, interleaved chains) ==========
    const int* abA = adj + bA * 45;
    const int* abB = adj + bB * 45;
    int avA = 0, avB = 0;
    if (lane < 45) { avA = abA[lane]; avB = abB[lane]; }
    const uint64_t amA = __ballot(avA != 0);
    const uint64_t amB = __ballot(avB != 0);

    float dA[9], dB[9];
#pragma unroll
    for (int i = 0; i < 9; ++i) {
        const int s = 9 * i - (i * (i - 1)) / 2;
        const uint64_t mk = (1ull << (8 - i)) - 1ull;
        dA[i] = __frsqrt_rn((float)(1 + __popcll((amA >> (s + 1)) & mk)));
        dB[i] = __frsqrt_rn((float)(1 + __popcll((amB >> (s + 1)) & mk)));
    }

    const float* xbA = x + bA * 63;
    const float* xbB = x + bB * 63;
    float yA = 0.f, yB = 0.f;
#pragma unroll
    for (int k = 0; k < 7; ++k) {
        const float g = gcn_W[k * 7 + f];            // shared across pair
        yA = fmaf(xbA[n * 7 + k], g, yA);
        yB = fmaf(xbB[n * 7 + k], g, yB);
    }

    // z dot: 3 accumulators per batch, chains interleaved
    float zA0 = 0.f, zA1 = 0.f, zA2 = 0.f, zB0 = 0.f, zB1 = 0.f, zB2 = 0.f;
    const int snn = 9 * n - (n * (n - 1)) / 2 - n;
#pragma unroll
    for (int m = 0; m < 9; ++m) {
        const float ymA = __shfl(yA, m * 7 + f);
        const float ymB = __shfl(yB, m * 7 + f);
        int sh = snn + m;
        sh = sh < 0 ? 0 : sh;
        const bool up = (m > n);
        const float tA = ((m == n) || (up && ((amA >> sh) & 1ull))) ? dA[m] : 0.f;
        const float tB = ((m == n) || (up && ((amB >> sh) & 1ull))) ? dB[m] : 0.f;
        if (m < 3)      { zA0 = fmaf(tA, ymA, zA0); zB0 = fmaf(tB, ymB, zB0); }
        else if (m < 6) { zA1 = fmaf(tA, ymA, zA1); zB1 = fmaf(tB, ymB, zB1); }
        else            { zA2 = fmaf(tA, ymA, zA2); zB2 = fmaf(tB, ymB, zB2); }
    }
    const float gbf = gcn_b[f];
    const float zvA = fmaf(dA[n], (zA0 + zA1) + zA2, gbf);
    const float zvB = fmaf(dB[n], (zB0 + zB1) + zB2, gbf);

    // ctx dots: ctx_W column loads SHARED across the pair; cb* wave-uniform
    const float* cbA = ctx + bA * 45;
    const float* cbB = ctx + bB * 45;
    const float cb0 = ctx_b[p];
    float aA0 = cb0, aA1 = 0.f, aA2 = 0.f, aA3 = 0.f;
    float aB0 = cb0, aB1 = 0.f, aB2 = 0.f, aB3 = 0.f;
#pragma unroll
    for (int q = 0; q < 44; q += 4) {
        const float w0 = ctx_W[q * 63 + p];
        const float w1 = ctx_W[(q + 1) * 63 + p];
        const float w2 = ctx_W[(q + 2) * 63 + p];
        const float w3 = ctx_W[(q + 3) * 63 + p];
        aA0 = fmaf(cbA[q],     w0, aA0);  aB0 = fmaf(cbB[q],     w0, aB0);
        aA1 = fmaf(cbA[q + 1], w1, aA1);  aB1 = fmaf(cbB[q + 1], w1, aB1);
        aA2 = fmaf(cbA[q + 2], w2, aA2);  aB2 = fmaf(cbB[q + 2], w2, aB2);
        aA3 = fmaf(cbA[q + 3], w3, aA3);  aB3 = fmaf(cbB[q + 3], w3, aB3);
    }
    const float w44 = ctx_W[44 * 63 + p];
    aA0 = fmaf(cbA[44], w44, aA0);  aB0 = fmaf(cbB[44], w44, aB0);
    const float cvA = fmaxf((aA0 + aA1) + (aA2 + aA3), 0.f);
    const float cvB = fmaxf((aB0 + aB1) + (aB2 + aB3), 0.f);

    // ========== PHASE 2: MFMA (operand-swapped, f16, dual-batch) ==========
    const int cl   = lane & 15;       // position within i-tile (B-operand n)
    const int quad = lane >> 4;       // k-octet / C row group (channel)
    const int s0 = (quad ^ (cl & 7)) * 16;

    float2 wp0[8], wp1[8];
    float  bb0[8], bb1[8];
#pragma unroll
    for (int j = 0; j < 8; ++j) {
        const int o = quad * 8 + j;
        wp0[j] = *(const float2*)(W1 + 2 * o);
        bb0[j] = b1[o];
        wp1[j] = *(const float2*)(W1 + 2 * (o + 32));
        bb1[j] = b1[o + 32];
    }

    const float4 b2q0 = *(const float4*)(b2 + quad * 4);
    const float4 b2q1 = *(const float4*)(b2 + 16 + quad * 4);
    const float4 b2q2 = *(const float4*)(b2 + 32 + quad * 4);
    const float4 b2q3 = *(const float4*)(b2 + 48 + quad * 4);
    const float4 wa0 = *(const float4*)(W3 + quad * 4);
    const float4 wa1 = *(const float4*)(W3 + 16 + quad * 4);
    const float4 wa2 = *(const float4*)(W3 + 32 + quad * 4);
    const float4 wa3 = *(const float4*)(W3 + 48 + quad * 4);
    const float4 wb0 = *(const float4*)(W3 + 64 + quad * 4);
    const float4 wb1 = *(const float4*)(W3 + 80 + quad * 4);
    const float4 wb2 = *(const float4*)(W3 + 96 + quad * 4);
    const float4 wb3 = *(const float4*)(W3 + 112 + quad * 4);
    const float b30 = b3[0], b31 = b3[1];
    float* __restrict__ obA = out + bA * 126;
    float* __restrict__ obB = out + bB * 126;

    const char* sh2bB_ = (const char*)sh2b;

    __syncthreads();   // staging complete before first B read

    // epilogue: relu + W3 dot on 16 channels, quad-reduce, store
    auto epilogue = [&](const f32x4& a0, const f32x4& a1,
                        const f32x4& a2, const f32x4& a3,
                        float* obp, int pp, bool valid) {
        float q0, q1, h;
        h = fmaxf(a0[0], 0.f); q0 = h * wa0.x;            q1 = h * wb0.x;
        h = fmaxf(a0[1], 0.f); q0 = fmaf(h, wa0.y, q0);   q1 = fmaf(h, wb0.y, q1);
        h = fmaxf(a0[2], 0.f); q0 = fmaf(h, wa0.z, q0);   q1 = fmaf(h, wb0.z, q1);
        h = fmaxf(a0[3], 0.f); q0 = fmaf(h, wa0.w, q0);   q1 = fmaf(h, wb0.w, q1);
        h = fmaxf(a1[0], 0.f); q0 = fmaf(h, wa1.x, q0);   q1 = fmaf(h, wb1.x, q1);
        h = fmaxf(a1[1], 0.f); q0 = fmaf(h, wa1.y, q0);   q1 = fmaf(h, wb1.y, q1);
        h = fmaxf(a1[2], 0.f); q0 = fmaf(h, wa1.z, q0);   q1 = fmaf(h, wb1.z, q1);
        h = fmaxf(a1[3], 0.f); q0 = fmaf(h, wa1.w, q0);   q1 = fmaf(h, wb1.w, q1);
        h = fmaxf(a2[0], 0.f); q0 = fmaf(h, wa2.x, q0);   q1 = fmaf(h, wb2.x, q1);
        h = fmaxf(a2[1], 0.f); q0 = fmaf(h, wa2.y, q0);   q1 = fmaf(h, wb2.y, q1);
        h = fmaxf(a2[2], 0.f); q0 = fmaf(h, wa2.z, q0);   q1 = fmaf(h, wb2.z, q1);
        h = fmaxf(a2[3], 0.f); q0 = fmaf(h, wa2.w, q0);   q1 = fmaf(h, wb2.w, q1);
        h = fmaxf(a3[0], 0.f); q0 = fmaf(h, wa3.x, q0);   q1 = fmaf(h, wb3.x, q1);
        h = fmaxf(a3[1], 0.f); q0 = fmaf(h, wa3.y, q0);   q1 = fmaf(h, wb3.y, q1);
        h = fmaxf(a3[2], 0.f); q0 = fmaf(h, wa3.z, q0);   q1 = fmaf(h, wb3.z, q1);
        h = fmaxf(a3[3], 0.f); q0 = fmaf(h, wa3.w, q0);   q1 = fmaf(h, wb3.w, q1);
        q0 += __shfl_xor(q0, 16); q0 += __shfl_xor(q0, 32);
        q1 += __shfl_xor(q1, 16); q1 += __shfl_xor(q1, 32);
        if (quad == 0 && pp < NPOS && valid) {
            obp[pp]        = q0 + b30;
            obp[NPOS + pp] = q1 + b31;
        }
    };

#pragma unroll 1
    for (int i = 0; i < 4; ++i) {
        const float zmA = __shfl(zvA, i * 16 + cl);
        const float cmA = __shfl(cvA, i * 16 + cl);
        const float zmB = __shfl(zvB, i * 16 + cl);
        const float cmB = __shfl(cvB, i * 16 + cl);

        // h1 fragments for both batches (interleaved independent chains)
        uint4v pA0, pA1, pB0, pB1;
#pragma unroll
        for (int jj = 0; jj < 4; ++jj) {
            const float2 u0 = wp0[2*jj],   u1 = wp0[2*jj+1];
            const float2 v0 = wp1[2*jj],   v1 = wp1[2*jj+1];
            const float  c0 = bb0[2*jj],   c1 = bb0[2*jj+1];
            const float  e0 = bb1[2*jj],   e1 = bb1[2*jj+1];

            float ha = fmaxf(fmaf(u0.x, zmA, fmaf(u0.y, cmA, c0)), 0.f);
            float hb = fmaxf(fmaf(u1.x, zmA, fmaf(u1.y, cmA, c1)), 0.f);
            pA0[jj] = pack_f16(ha, hb);
            ha = fmaxf(fmaf(v0.x, zmA, fmaf(v0.y, cmA, e0)), 0.f);
            hb = fmaxf(fmaf(v1.x, zmA, fmaf(v1.y, cmA, e1)), 0.f);
            pA1[jj] = pack_f16(ha, hb);

            ha = fmaxf(fmaf(u0.x, zmB, fmaf(u0.y, cmB, c0)), 0.f);
            hb = fmaxf(fmaf(u1.x, zmB, fmaf(u1.y, cmB, c1)), 0.f);
            pB0[jj] = pack_f16(ha, hb);
            ha = fmaxf(fmaf(v0.x, zmB, fmaf(v0.y, cmB, e0)), 0.f);
            hb = fmaxf(fmaf(v1.x, zmB, fmaf(v1.y, cmB, e1)), 0.f);
            pB1[jj] = pack_f16(ha, hb);
        }
        const f16x8 ahA0 = __builtin_bit_cast(f16x8, pA0);
        const f16x8 ahA1 = __builtin_bit_cast(f16x8, pA1);
        const f16x8 ahB0 = __builtin_bit_cast(f16x8, pB0);
        const f16x8 ahB1 = __builtin_bit_cast(f16x8, pB1);

        f32x4 accA0 = {b2q0.x, b2q0.y, b2q0.z, b2q0.w};
        f32x4 accA1 = {b2q1.x, b2q1.y, b2q1.z, b2q1.w};
        f32x4 accA2 = {b2q2.x, b2q2.y, b2q2.z, b2q2.w};
        f32x4 accA3 = {b2q3.x, b2q3.y, b2q3.z, b2q3.w};
        f32x4 accB0 = accA0, accB1 = accA1, accB2 = accA2, accB3 = accA3;

        // A-operand W2 LDS reads shared by BOTH batches: 2 ds_read_b128
        // feed 4 MFMAs per STEP (A/B interleaved = independent, hides
        // MFMA latency).
#define STEP(nt) {                                                                      \
        int bo = cl * 128 + s0;                                                         \
        asm volatile("" : "+v"(bo));                                                    \
        const int bo2 = (cl * 128) | (s0 ^ 64);                                         \
        const f16x8 wf0 = *(const f16x8*)(sh2bB_ + bo  + ((nt) * 2048));                \
        const f16x8 wf1 = *(const f16x8*)(sh2bB_ + bo2 + ((nt) * 2048));                \
        accA##nt = __builtin_amdgcn_mfma_f32_16x16x32_f16(wf0, ahA0, accA##nt, 0, 0, 0); \
        accB##nt = __builtin_amdgcn_mfma_f32_16x16x32_f16(wf0, ahB0, accB##nt, 0, 0, 0); \
        accA##nt = __builtin_amdgcn_mfma_f32_16x16x32_f16(wf1, ahA1, accA##nt, 0, 0, 0); \
        accB##nt = __builtin_amdgcn_mfma_f32_16x16x32_f16(wf1, ahB1, accB##nt, 0, 0, 0); }
        STEP(0) STEP(1) STEP(2) STEP(3)
#undef STEP

        const int pp = i * 16 + cl;
        epilogue(accA0, accA1, accA2, accA3, obA, pp, true);
        epilogue(accB0, accB1, accB2, accB3, obB, pp, hasB);
    }
}

extern "C" void kernel_launch(void* const* d_in, const int* in_sizes, int n_in,
                              void* d_out, int out_size, void* d_ws, size_t ws_size,
                              hipStream_t stream) {
    const float* x     = (const float*)d_in[0];
    const int*   adj   = (const int*)  d_in[1];
    const float* ctx   = (const float*)d_in[2];
    const float* gcn_W = (const float*)d_in[3];
    const float* gcn_b = (const float*)d_in[4];
    const float* ctx_W = (const float*)d_in[5];
    const float* ctx_b = (const float*)d_in[6];
    const float* W1    = (const float*)d_in[7];
    const float* b1    = (const float*)d_in[8];
    const float* W2    = (const float*)d_in[9];
    const float* b2    = (const float*)d_in[10];
    const float* W3    = (const float*)d_in[11];
    const float* b3    = (const float*)d_in[12];
    float* out = (float*)d_out;

    const int nbatch = in_sizes[1] / 45;            // B = 32768
    const int grid = (nbatch + BPB - 1) / BPB;      // 8 batches per block
    carnet_fused<<<grid, BLOCK_SIZE, 0, stream>>>(
        x, adj, ctx, gcn_W, gcn_b, ctx_W, ctx_b,
        W1, b1, W2, b2, W3, b3, out, nbatch);
}